// Round 19
// baseline (367.344 us; speedup 1.0000x reference)
//
#include <hip/hip_runtime.h>
#include <cstdint>
#include <cstddef>

#define NN 50000
#define EE 800000
#define NT 5   // 16-edge tiles per wave; 2500 blocks * 4 waves * NT * 16 == EE

typedef short bf16x8 __attribute__((ext_vector_type(8)));
typedef float f32x4 __attribute__((ext_vector_type(4)));
typedef float fx4 __attribute__((ext_vector_type(4)));

static __device__ __forceinline__ ushort f2b(float f) {
  uint u = __builtin_bit_cast(uint, f);
  u += 0x7FFFu + ((u >> 16) & 1u);
  return (ushort)(u >> 16);
}
static __device__ __forceinline__ float b2f(ushort h) {
  return __builtin_bit_cast(float, ((uint)h) << 16);
}
static __device__ __forceinline__ uint pk2(float a, float b) {
  return (uint)f2b(a) | (((uint)f2b(b)) << 16);
}
static __device__ __forceinline__ void up8(uint4 u, float* o) {
  o[0] = b2f((ushort)(u.x & 0xFFFF)); o[1] = b2f((ushort)(u.x >> 16));
  o[2] = b2f((ushort)(u.y & 0xFFFF)); o[3] = b2f((ushort)(u.y >> 16));
  o[4] = b2f((ushort)(u.z & 0xFFFF)); o[5] = b2f((ushort)(u.z >> 16));
  o[6] = b2f((ushort)(u.w & 0xFFFF)); o[7] = b2f((ushort)(u.w >> 16));
}
static __device__ __forceinline__ fx4 up4(uint2 u) {
  fx4 o;
  o[0] = b2f((ushort)(u.x & 0xFFFF)); o[1] = b2f((ushort)(u.x >> 16));
  o[2] = b2f((ushort)(u.y & 0xFFFF)); o[3] = b2f((ushort)(u.y >> 16));
  return o;
}
// build one MFMA frag word of a [K x 64] weight matrix (K=128 or K=64)
static __device__ __forceinline__ uint4 mk_frag(const float* W, int i) {
  int s2 = i >> 8, n = (i >> 6) & 3, lane = i & 63;
  int lo = lane & 15, hi = lane >> 4;
  ushort h[8];
#pragma unroll
  for (int j = 0; j < 8; j++) h[j] = f2b(W[(s2 * 32 + hi * 8 + j) * 64 + lo + 16 * n]);
  uint4 u;
  u.x = (uint)h[0] | ((uint)h[1] << 16); u.y = (uint)h[2] | ((uint)h[3] << 16);
  u.z = (uint)h[4] | ((uint)h[5] << 16); u.w = (uint)h[6] | ((uint)h[7] << 16);
  return u;
}

// ---------- K0: pack Wm/We/Wl/Wr into MFMA frag-ordered uint4 tables ----------
__global__ __launch_bounds__(256) void k_prep(const float* __restrict__ Wm,
                                              const float* __restrict__ We,
                                              const float* __restrict__ Wl,
                                              const float* __restrict__ Wr,
                                              uint4* __restrict__ wmP,
                                              uint4* __restrict__ weP,
                                              uint4* __restrict__ wlP,
                                              uint4* __restrict__ wrP) {
  int idx = blockIdx.x * 256 + threadIdx.x;  // 10 blocks * 256 = 2560
  if (idx < 1024) wmP[idx] = mk_frag(Wm, idx);
  else if (idx < 1536) weP[idx - 1024] = mk_frag(We, idx - 1024);
  else if (idx < 2048) wlP[idx - 1536] = mk_frag(Wl, idx - 1536);
  else if (idx < 2560) wrP[idx - 2048] = mk_frag(Wr, idx - 2048);
}

// ---------- K1 (ws path): xlb = bf16(x@Wl), xrb = bf16(x@Wr) via MFMA ----------
__global__ __launch_bounds__(256) void k_node_linear_mfma(
    const float* __restrict__ x, const uint4* __restrict__ wlP,
    const uint4* __restrict__ wrP, ushort* __restrict__ xlb,
    ushort* __restrict__ xrb, int n) {
  __shared__ float sT[4][2][16 * 68];
  int tid = threadIdx.x;
  int w = tid >> 6, l = tid & 63;
  int lo16 = l & 15, hi4 = l >> 4;
  bf16x8 awl[4][2], awr[4][2];
#pragma unroll
  for (int s = 0; s < 2; s++)
#pragma unroll
    for (int nn = 0; nn < 4; nn++) {
      awl[nn][s] = __builtin_bit_cast(bf16x8, wlP[(s * 4 + nn) * 64 + l]);
      awr[nn][s] = __builtin_bit_cast(bf16x8, wrP[(s * 4 + nn) * 64 + l]);
    }
  int ntile = (blockIdx.x * 4 + w) * 16;
  if (ntile >= n) return;
  int node = ntile + lo16;
  bf16x8 bfr[2];
#pragma unroll
  for (int s2 = 0; s2 < 2; s2++) {
    const fx4* p = (const fx4*)(x + (size_t)node * 64 + s2 * 32 + hi4 * 8);
    fx4 f0 = p[0];
    fx4 f1 = p[1];
    uint4 u;
    u.x = pk2(f0[0], f0[1]); u.y = pk2(f0[2], f0[3]);
    u.z = pk2(f1[0], f1[1]); u.w = pk2(f1[2], f1[3]);
    bfr[s2] = __builtin_bit_cast(bf16x8, u);
  }
  f32x4 z4 = {0.f, 0.f, 0.f, 0.f};
  f32x4 accl[4] = {z4, z4, z4, z4};
  f32x4 accr[4] = {z4, z4, z4, z4};
#pragma unroll
  for (int s2 = 0; s2 < 2; s2++)
#pragma unroll
    for (int nn = 0; nn < 4; nn++) {
      accl[nn] = __builtin_amdgcn_mfma_f32_16x16x32_bf16(awl[nn][s2], bfr[s2], accl[nn], 0, 0, 0);
      accr[nn] = __builtin_amdgcn_mfma_f32_16x16x32_bf16(awr[nn][s2], bfr[s2], accr[nn], 0, 0, 0);
    }
#pragma unroll
  for (int nn = 0; nn < 4; nn++)
#pragma unroll
    for (int r = 0; r < 4; r++) {
      sT[w][0][lo16 * 68 + hi4 * 4 + r + 16 * nn] = accl[nn][r];
      sT[w][1][lo16 * 68 + hi4 * 4 + r + 16 * nn] = accr[nn][r];
    }
  int m2 = l >> 2, q2 = l & 3;
#pragma unroll
  for (int b = 0; b < 2; b++) {
    float v[16];
#pragma unroll
    for (int c = 0; c < 16; c++) v[c] = sT[w][b][m2 * 68 + q2 * 16 + c];
    uint4 u0, u1;
    u0.x = pk2(v[0], v[1]);  u0.y = pk2(v[2], v[3]);
    u0.z = pk2(v[4], v[5]);  u0.w = pk2(v[6], v[7]);
    u1.x = pk2(v[8], v[9]);  u1.y = pk2(v[10], v[11]);
    u1.z = pk2(v[12], v[13]); u1.w = pk2(v[14], v[15]);
    ushort* dst = (b ? xrb : xlb) + (size_t)(ntile + m2) * 64 + q2 * 16;
    ((uint4*)dst)[0] = u0;
    ((uint4*)dst)[1] = u1;
  }
}

// ---------- K1 fallback: f32 xl/xr via VALU ----------
__global__ __launch_bounds__(256, 3) void k_node_linear(
    const float* __restrict__ x, const float* __restrict__ Wl,
    const float* __restrict__ Wr, float* __restrict__ xl,
    float* __restrict__ xr, int n) {
  int i = blockIdx.x * 256 + threadIdx.x;
  if (i >= n) return;
  const float4* px = (const float4*)(x + (size_t)i * 64);
  float accl[64], accr[64];
#pragma unroll
  for (int c = 0; c < 64; c++) { accl[c] = 0.f; accr[c] = 0.f; }
  for (int kq = 0; kq < 16; kq++) {
    float4 v = px[kq];
#pragma unroll
    for (int j = 0; j < 4; j++) {
      float xv = (j == 0) ? v.x : (j == 1) ? v.y : (j == 2) ? v.z : v.w;
      const float* wl = Wl + (kq * 4 + j) * 64;
      const float* wr = Wr + (kq * 4 + j) * 64;
#pragma unroll
      for (int c = 0; c < 64; c++) {
        accl[c] = fmaf(xv, wl[c], accl[c]);
        accr[c] = fmaf(xv, wr[c], accr[c]);
      }
    }
  }
  float4* pl = (float4*)(xl + (size_t)i * 64);
  float4* pr = (float4*)(xr + (size_t)i * 64);
#pragma unroll
  for (int q = 0; q < 16; q++) {
    float4 a, b;
    a.x = accl[4 * q]; a.y = accl[4 * q + 1]; a.z = accl[4 * q + 2]; a.w = accl[4 * q + 3];
    b.x = accr[4 * q]; b.y = accr[4 * q + 1]; b.z = accr[4 * q + 2]; b.w = accr[4 * q + 3];
    pl[q] = a; pr[q] = b;
  }
}

// ---------- K2: logits via MFMA -> exp; gather + ea both software-pipelined ----------
template <bool PACKED>
__global__ __launch_bounds__(256) void k_edge_logits(
    const float* __restrict__ ea, const int* __restrict__ ei,
    const float* __restrict__ We, const float* __restrict__ att,
    const float* __restrict__ xl, const float* __restrict__ xr,
    const ushort* __restrict__ xlb, const ushort* __restrict__ xrb,
    const uint4* __restrict__ weP, float* __restrict__ pexp,
    int* __restrict__ counts) {
  int tid = threadIdx.x;
  int w = tid >> 6, l = tid & 63;
  int lo16 = l & 15, hi4 = l >> 4;
  bf16x8 aw[4][2];
  if (PACKED) {
#pragma unroll
    for (int s = 0; s < 2; s++)
#pragma unroll
      for (int n = 0; n < 4; n++)
        aw[n][s] = __builtin_bit_cast(bf16x8, weP[(s * 4 + n) * 64 + l]);
  } else {
    for (int n = 0; n < 4; n++)
      for (int s = 0; s < 2; s++)
        aw[n][s] = __builtin_bit_cast(bf16x8, mk_frag(We, (s * 4 + n) * 64 + l));
  }
  float att4[4][4];
#pragma unroll
  for (int n = 0; n < 4; n++) {
    float4 a = *(const float4*)(att + 16 * n + hi4 * 4);
    att4[n][0] = a.x; att4[n][1] = a.y; att4[n][2] = a.z; att4[n][3] = a.w;
  }
  int wgid = blockIdx.x * 4 + w;
  int ebase = wgid * NT * 16;
  int sj = ei[ebase + lo16], dj = ei[EE + ebase + lo16];
  // prologue: tile-0 gathers + tile-0 ea
  uint2 grl[4], grr[4];
  if (PACKED) {
#pragma unroll
    for (int n = 0; n < 4; n++) {
      grl[n] = *(const uint2*)(xlb + (size_t)sj * 64 + 16 * n + hi4 * 4);
      grr[n] = *(const uint2*)(xrb + (size_t)dj * 64 + 16 * n + hi4 * 4);
    }
  }
  fx4 ear[4];
#pragma unroll
  for (int s2 = 0; s2 < 2; s2++) {
    const fx4* p = (const fx4*)(ea + (size_t)(ebase + lo16) * 64 + s2 * 32 + hi4 * 8);
    ear[s2 * 2] = p[0];
    ear[s2 * 2 + 1] = p[1];
  }
  for (int it = 0; it < NT; it++) {
    int er = ebase + it * 16 + lo16;
    int djc = dj;
    fx4 gl[4], gr[4];
    if (!PACKED) {
#pragma unroll
      for (int n = 0; n < 4; n++) {
        gl[n] = *(const fx4*)(xl + (size_t)sj * 64 + 16 * n + hi4 * 4);
        gr[n] = *(const fx4*)(xr + (size_t)dj * 64 + 16 * n + hi4 * 4);
      }
    }
    // prefetch next tile's indices
    int sjn = 0, djn = 0;
    if (it + 1 < NT) {
      sjn = ei[er + 16];
      djn = ei[EE + er + 16];
    }
    // pack current ea -> bfr
    bf16x8 bfr[2];
#pragma unroll
    for (int s2 = 0; s2 < 2; s2++) {
      fx4 f0 = ear[s2 * 2], f1 = ear[s2 * 2 + 1];
      uint4 u;
      u.x = pk2(f0[0], f0[1]); u.y = pk2(f0[2], f0[3]);
      u.z = pk2(f1[0], f1[1]); u.w = pk2(f1[2], f1[3]);
      bfr[s2] = __builtin_bit_cast(bf16x8, u);
    }
    // issue next tile's ea loads (full MFMA+epilogue to land)
    if (it + 1 < NT) {
#pragma unroll
      for (int s2 = 0; s2 < 2; s2++) {
        const fx4* p = (const fx4*)(ea + (size_t)(er + 16) * 64 + s2 * 32 + hi4 * 8);
        ear[s2 * 2] = p[0];
        ear[s2 * 2 + 1] = p[1];
      }
    }
    f32x4 z4 = {0.f, 0.f, 0.f, 0.f};
    f32x4 acc[4] = {z4, z4, z4, z4};
#pragma unroll
    for (int s2 = 0; s2 < 2; s2++)
#pragma unroll
      for (int n = 0; n < 4; n++)
        acc[n] = __builtin_amdgcn_mfma_f32_16x16x32_bf16(aw[n][s2], bfr[s2], acc[n], 0, 0, 0);
    if (PACKED) {
#pragma unroll
      for (int n = 0; n < 4; n++) { gl[n] = up4(grl[n]); gr[n] = up4(grr[n]); }
    }
    float lg[4];
#pragma unroll
    for (int n = 0; n < 4; n++) {
      float s = 0.f;
#pragma unroll
      for (int r = 0; r < 4; r++) {
        float z = acc[n][r] + gl[n][r] + gr[n][r];
        z = (z >= 0.f) ? z : 0.2f * z;
        s += z * att4[n][r];
      }
      s += __shfl_xor(s, 16, 64);
      s += __shfl_xor(s, 32, 64);
      lg[n] = s;
    }
    if (hi4 == 0) {
      // store exp(logit): max-subtraction unnecessary (|logit| ~ O(1)) and
      // softmax is shift-invariant.
      fx4 o = {__expf(lg[0]), __expf(lg[1]), __expf(lg[2]), __expf(lg[3])};
      ((fx4*)pexp)[er] = o;
      atomicAdd(&counts[djc], 1);
    }
    // issue next tile's gathers
    if (it + 1 < NT) {
      sj = sjn; dj = djn;
      if (PACKED) {
#pragma unroll
        for (int n = 0; n < 4; n++) {
          grl[n] = *(const uint2*)(xlb + (size_t)sj * 64 + 16 * n + hi4 * 4);
          grr[n] = *(const uint2*)(xrb + (size_t)dj * 64 + 16 * n + hi4 * 4);
        }
      }
    }
  }
}

// ---------- K3a/b/c: hierarchical exclusive scan of counts ----------
__global__ __launch_bounds__(256) void k_scan_sum(const int* __restrict__ counts,
                                                  int* __restrict__ bsum, int n) {
  __shared__ int red[256];
  int t = threadIdx.x;
  int idx = blockIdx.x * 256 + t;
  red[t] = (idx < n) ? counts[idx] : 0;
  __syncthreads();
  for (int off = 128; off > 0; off >>= 1) {
    if (t < off) red[t] += red[t + off];
    __syncthreads();
  }
  if (t == 0) bsum[blockIdx.x] = red[0];
}
__global__ __launch_bounds__(256) void k_scan_blk(const int* __restrict__ bsum,
                                                  int* __restrict__ boff,
                                                  int* __restrict__ offsets_end, int nb) {
  __shared__ int tmp[256];
  int t = threadIdx.x;
  int v = (t < nb) ? bsum[t] : 0;
  tmp[t] = v;
  __syncthreads();
  for (int off = 1; off < 256; off <<= 1) {
    int u = (t >= off) ? tmp[t - off] : 0;
    __syncthreads();
    tmp[t] += u;
    __syncthreads();
  }
  if (t < nb) boff[t] = tmp[t] - v;
  if (t == 255) offsets_end[0] = tmp[255];
}
__global__ __launch_bounds__(256) void k_scan_apply(const int* __restrict__ counts,
                                                    const int* __restrict__ boff,
                                                    int* __restrict__ offsets,
                                                    int* __restrict__ cursor, int n) {
  __shared__ int tmp[256];
  int t = threadIdx.x;
  int idx = blockIdx.x * 256 + t;
  int v = (idx < n) ? counts[idx] : 0;
  tmp[t] = v;
  __syncthreads();
  for (int off = 1; off < 256; off <<= 1) {
    int u = (t >= off) ? tmp[t - off] : 0;
    __syncthreads();
    tmp[t] += u;
    __syncthreads();
  }
  if (idx < n) {
    int ex = boff[blockIdx.x] + tmp[t] - v;
    offsets[idx] = ex;
    cursor[idx] = ex;
  }
}

// ---------- K4: scatter src + pexp payload into CSR order ----------
__global__ __launch_bounds__(256) void k_scatter(const int* __restrict__ ei,
                                                 const float* __restrict__ pexp,
                                                 int* __restrict__ cursor,
                                                 int* __restrict__ srcs,
                                                 float* __restrict__ pscr, int ne) {
  int e = blockIdx.x * blockDim.x + threadIdx.x;
  if (e < ne) {
    int d = ei[EE + e];
    int s = ei[e];
    fx4 p = ((const fx4*)pexp)[e];
    int pos = atomicAdd(&cursor[d], 1);
    srcs[pos] = s;
    ((fx4*)pscr)[pos] = p;
  }
}

// ---------- K5: segment aggregate over CSR-ordered payload ----------
template <bool BF>
__global__ __launch_bounds__(256) void k_node_agg(
    const int* __restrict__ offsets, const int* __restrict__ srcs,
    const float* __restrict__ pscr, const float* __restrict__ xl,
    const ushort* __restrict__ xlb, const float* __restrict__ bias,
    float* __restrict__ xout, ushort* __restrict__ xb, int n) {
  int tid = threadIdx.x;
  int y = tid >> 6, l = tid & 63;
  int h = l >> 4;
  float bv = bias[l];
  int i = blockIdx.x * 4 + y;
  if (i >= n) return;  // wave-uniform
  int beg = offsets[i], end = offsets[i + 1];
  float den = 0.f, acc = 0.f;
  for (int c0 = beg; c0 < end; c0 += 64) {
    int cnt = min(64, end - c0);
    int s_l = (l < cnt) ? srcs[c0 + l] : 0;   // coalesced
    for (int j = 0; j < cnt; j += 8) {
      int nb8 = min(8, cnt - j);
      float pv[8], xvf[8];
      ushort xvb[8];
#pragma unroll
      for (int u = 0; u < 8; u++) {
        if (u < nb8) {
          int su = __shfl(s_l, j + u, 64);
          pv[u] = pscr[(size_t)(c0 + j + u) * 4 + h];   // sequential in node range
          if (BF) xvb[u] = xlb[(size_t)su * 64 + l];
          else xvf[u] = xl[(size_t)su * 64 + l];
        }
      }
#pragma unroll
      for (int u = 0; u < 8; u++) {
        if (u < nb8) {
          den += pv[u];
          acc = fmaf(pv[u], BF ? b2f(xvb[u]) : xvf[u], acc);
        }
      }
    }
  }
  float o = acc / (den + 1e-16f) + bv;
  xout[(size_t)i * 64 + l] = o;
  if (BF) xb[(size_t)i * 64 + l] = f2b(o);
}

// ---------- K6: edge MLP via MFMA; half weights in LDS, ea residual pipelined ----------
template <bool PACKED>
__global__ __launch_bounds__(256) void k_edge_mlp(
    const float* __restrict__ ea, const int* __restrict__ ei,
    const float* __restrict__ xoutf, const ushort* __restrict__ xb,
    const float* __restrict__ lng, const float* __restrict__ lnb,
    const float* __restrict__ Wm, const uint4* __restrict__ wmP,
    const float* __restrict__ bm, float* __restrict__ eout) {
  __shared__ float sT[4][16 * 68];
  __shared__ uint4 sWm[512];   // Wm frags for s2=2,3 (block-shared, 8 KB)
  int tid = threadIdx.x;
  int w = tid >> 6, l = tid & 63;
  int lo16 = l & 15, hi4 = l >> 4;
  // fill LDS weight slice (s2=2,3): wmP[(s2*4+n)*64+lane] for s2>=2 -> idx 512..1023
  if (PACKED) {
    for (int i = tid; i < 512; i += 256) sWm[i] = wmP[512 + i];
  } else {
    for (int i = tid; i < 512; i += 256) sWm[i] = mk_frag(Wm, 512 + i);
  }
  // register weight slice (s2=0,1)
  bf16x8 bwmR[4][2];
  if (PACKED) {
#pragma unroll
    for (int s2 = 0; s2 < 2; s2++)
#pragma unroll
      for (int n = 0; n < 4; n++)
        bwmR[n][s2] = __builtin_bit_cast(bf16x8, wmP[(s2 * 4 + n) * 64 + l]);
  } else {
    for (int n = 0; n < 4; n++)
      for (int s2 = 0; s2 < 2; s2++)
        bwmR[n][s2] = __builtin_bit_cast(bf16x8, mk_frag(Wm, (s2 * 4 + n) * 64 + l));
  }
  float bmv[4];
#pragma unroll
  for (int n = 0; n < 4; n++) bmv[n] = bm[lo16 + 16 * n];
  __syncthreads();

  int wgid = blockIdx.x * 4 + w;
  int ebase = wgid * NT * 16;
  int m2 = l >> 2, q2 = l & 3;

  int sj = ei[ebase + lo16], dj = ei[EE + ebase + lo16];
  uint4 pf0, pf1, pf2, pf3;
  if (PACKED) {
    pf0 = *(const uint4*)(xb + (size_t)sj * 64 + hi4 * 8);
    pf1 = *(const uint4*)(xb + (size_t)sj * 64 + 32 + hi4 * 8);
    pf2 = *(const uint4*)(xb + (size_t)dj * 64 + hi4 * 8);
    pf3 = *(const uint4*)(xb + (size_t)dj * 64 + 32 + hi4 * 8);
  }
  // prologue: tile-0 ea residual (per-lane epilogue slice)
  fx4 earn[4];
#pragma unroll
  for (int c = 0; c < 4; c++)
    earn[c] = *(const fx4*)(ea + (size_t)(ebase + m2) * 64 + q2 * 16 + 4 * c);

  for (int it = 0; it < NT; it++) {
    int e0 = ebase + it * 16;
    float vv[4][8];
    if (PACKED) {
      up8(pf0, vv[0]); up8(pf1, vv[1]); up8(pf2, vv[2]); up8(pf3, vv[3]);
    } else {
#pragma unroll
      for (int s2 = 0; s2 < 4; s2++) {
        const float* src = (s2 < 2) ? (xoutf + (size_t)sj * 64 + (s2 & 1) * 32 + hi4 * 8)
                                    : (xoutf + (size_t)dj * 64 + (s2 & 1) * 32 + hi4 * 8);
        float4 a = *(const float4*)src;
        float4 b = *(const float4*)(src + 4);
        vv[s2][0] = a.x; vv[s2][1] = a.y; vv[s2][2] = a.z; vv[s2][3] = a.w;
        vv[s2][4] = b.x; vv[s2][5] = b.y; vv[s2][6] = b.z; vv[s2][7] = b.w;
      }
    }
    int sjn = 0, djn = 0;
    if (it + 1 < NT) {
      sjn = ei[e0 + 16 + lo16];
      djn = ei[EE + e0 + 16 + lo16];
    }
    float sm = 0.f, sq = 0.f;
#pragma unroll
    for (int s2 = 0; s2 < 4; s2++)
#pragma unroll
      for (int j = 0; j < 8; j++) { sm += vv[s2][j]; sq += vv[s2][j] * vv[s2][j]; }
    sm += __shfl_xor(sm, 16, 64); sm += __shfl_xor(sm, 32, 64);
    sq += __shfl_xor(sq, 16, 64); sq += __shfl_xor(sq, 32, 64);
    float mean = sm * (1.f / 128.f);
    float var = sq * (1.f / 128.f) - mean * mean;
    float rs = rsqrtf(var + 1e-5f);
    f32x4 acc[4];
#pragma unroll
    for (int n = 0; n < 4; n++) {
      f32x4 c = {bmv[n], bmv[n], bmv[n], bmv[n]};
      acc[n] = c;
    }
#pragma unroll
    for (int s2 = 0; s2 < 4; s2++) {
      float4 ga = *(const float4*)(lng + s2 * 32 + hi4 * 8);
      float4 gb = *(const float4*)(lng + s2 * 32 + hi4 * 8 + 4);
      float4 ba = *(const float4*)(lnb + s2 * 32 + hi4 * 8);
      float4 bb = *(const float4*)(lnb + s2 * 32 + hi4 * 8 + 4);
      float g8[8] = {ga.x, ga.y, ga.z, ga.w, gb.x, gb.y, gb.z, gb.w};
      float b8[8] = {ba.x, ba.y, ba.z, ba.w, bb.x, bb.y, bb.z, bb.w};
      float h8[8];
#pragma unroll
      for (int j = 0; j < 8; j++)
        h8[j] = fmaxf(fmaf((vv[s2][j] - mean) * rs, g8[j], b8[j]), 0.f);
      uint4 u;
      u.x = pk2(h8[0], h8[1]); u.y = pk2(h8[2], h8[3]);
      u.z = pk2(h8[4], h8[5]); u.w = pk2(h8[6], h8[7]);
      bf16x8 afr = __builtin_bit_cast(bf16x8, u);
#pragma unroll
      for (int n = 0; n < 4; n++) {
        bf16x8 bw = (s2 < 2)
            ? bwmR[n][s2]
            : __builtin_bit_cast(bf16x8, sWm[(s2 - 2) * 256 + n * 64 + l]);
        acc[n] = __builtin_amdgcn_mfma_f32_16x16x32_bf16(afr, bw, acc[n], 0, 0, 0);
      }
    }
    if (it + 1 < NT) {
      if (PACKED) {
        pf0 = *(const uint4*)(xb + (size_t)sjn * 64 + hi4 * 8);
        pf1 = *(const uint4*)(xb + (size_t)sjn * 64 + 32 + hi4 * 8);
        pf2 = *(const uint4*)(xb + (size_t)djn * 64 + hi4 * 8);
        pf3 = *(const uint4*)(xb + (size_t)djn * 64 + 32 + hi4 * 8);
      }
      sj = sjn; dj = djn;
    }
#pragma unroll
    for (int n = 0; n < 4; n++)
#pragma unroll
      for (int r = 0; r < 4; r++)
        sT[w][(hi4 * 4 + r) * 68 + lo16 + 16 * n] = acc[n][r];
    // epilogue: consume this tile's prefetched ea, then issue next tile's
#pragma unroll
    for (int c = 0; c < 4; c++) {
      fx4 t4 = *(const fx4*)&sT[w][m2 * 68 + q2 * 16 + 4 * c];
      size_t off = (size_t)(e0 + m2) * 64 + q2 * 16 + 4 * c;
      fx4 o = earn[c] + t4;
      *(fx4*)(eout + off) = o;
    }
    if (it + 1 < NT) {
#pragma unroll
      for (int c = 0; c < 4; c++)
        earn[c] = *(const fx4*)(ea + (size_t)(e0 + 16 + m2) * 64 + q2 * 16 + 4 * c);
    }
  }
}

extern "C" void kernel_launch(void* const* d_in, const int* in_sizes, int n_in,
                              void* d_out, int out_size, void* d_ws, size_t ws_size,
                              hipStream_t stream) {
  const float* x   = (const float*)d_in[0];
  const int*   ei  = (const int*)d_in[1];
  const float* ea  = (const float*)d_in[2];
  const float* Wl  = (const float*)d_in[3];
  const float* Wr  = (const float*)d_in[4];
  const float* We  = (const float*)d_in[5];
  const float* att = (const float*)d_in[6];
  const float* cb  = (const float*)d_in[7];
  const float* lng = (const float*)d_in[8];
  const float* lnb = (const float*)d_in[9];
  const float* Wm  = (const float*)d_in[10];
  const float* bm  = (const float*)d_in[11];

  float* out  = (float*)d_out;
  float* xout = out;                       // [N,64]
  float* eout = out + (size_t)NN * 64;     // [E,64]

  const int nb = (NN + 255) / 256;         // 196 scan blocks
  const int egrid = EE / (4 * NT * 16);    // 2500 blocks for edge kernels

  size_t packBytes = (size_t)(1024 + 512 + 512 + 512) * 16;        // wmP+weP+wlP+wrP
  size_t fWords    = (size_t)NN * 64 * 2 + (size_t)EE * 4 * 2;     // xl, xr, pexp, pscr
  size_t xbWords   = (size_t)NN * 64 / 2;                          // bf16 x_out
  size_t xlbWords  = (size_t)NN * 64 / 2;                          // bf16 xl
  size_t xrbWords  = (size_t)NN * 64 / 2;                          // bf16 xr
  size_t intWords  = (size_t)NN * 3 + 1 + (size_t)EE + 512;        // counts/off/cur/srcs/bsum/boff
  size_t needBytes = packBytes + (fWords + xbWords + xlbWords + xrbWords + intWords) * 4;
  bool useWs = (ws_size >= needBytes);

  uint4*  wmP = useWs ? (uint4*)d_ws : nullptr;
  uint4*  weP = useWs ? wmP + 1024 : nullptr;
  uint4*  wlP = useWs ? weP + 512 : nullptr;
  uint4*  wrP = useWs ? wlP + 512 : nullptr;
  float*  fbase = useWs ? (float*)((char*)d_ws + packBytes) : eout;

  float*  xl      = fbase;
  float*  xr      = xl + (size_t)NN * 64;
  float*  pexp    = xr + (size_t)NN * 64;
  float*  pscr    = pexp + (size_t)EE * 4;
  ushort* xb      = useWs ? (ushort*)(pscr + (size_t)EE * 4) : nullptr;
  ushort* xlb     = useWs ? xb + (size_t)NN * 64 : nullptr;
  ushort* xrb     = useWs ? xlb + (size_t)NN * 64 : nullptr;
  int*    counts  = useWs ? (int*)(xrb + (size_t)NN * 64)
                          : (int*)(pscr + (size_t)EE * 4);
  int*    offsets = counts + NN;
  int*    cursor  = offsets + NN + 1;
  int*    srcs    = cursor + NN;
  int*    bsum    = srcs + EE;
  int*    boff    = bsum + 256;

  hipMemsetAsync(counts, 0, NN * sizeof(int), stream);
  if (useWs) {
    k_prep<<<10, 256, 0, stream>>>(Wm, We, Wl, Wr, wmP, weP, wlP, wrP);
    k_node_linear_mfma<<<(NN / 16 + 3) / 4, 256, 0, stream>>>(x, wlP, wrP, xlb, xrb, NN);
    k_edge_logits<true><<<egrid, 256, 0, stream>>>(ea, ei, We, att, xl, xr, xlb, xrb, weP, pexp, counts);
  } else {
    k_node_linear<<<(NN + 255) / 256, 256, 0, stream>>>(x, Wl, Wr, xl, xr, NN);
    k_edge_logits<false><<<egrid, 256, 0, stream>>>(ea, ei, We, att, xl, xr, nullptr, nullptr, nullptr, pexp, counts);
  }
  k_scan_sum<<<nb, 256, 0, stream>>>(counts, bsum, NN);
  k_scan_blk<<<1, 256, 0, stream>>>(bsum, boff, offsets + NN, nb);
  k_scan_apply<<<nb, 256, 0, stream>>>(counts, boff, offsets, cursor, NN);
  k_scatter<<<(EE + 255) / 256, 256, 0, stream>>>(ei, pexp, cursor, srcs, pscr, EE);
  if (useWs)
    k_node_agg<true><<<(NN + 3) / 4, 256, 0, stream>>>(offsets, srcs, pscr, xl, xlb, cb, xout, xb, NN);
  else
    k_node_agg<false><<<(NN + 3) / 4, 256, 0, stream>>>(offsets, srcs, pscr, xl, nullptr, cb, xout, nullptr, NN);
  if (useWs)
    k_edge_mlp<true><<<egrid, 256, 0, stream>>>(ea, ei, xout, xb, lng, lnb, Wm, wmP, bm, eout);
  else
    k_edge_mlp<false><<<egrid, 256, 0, stream>>>(ea, ei, xout, nullptr, lng, lnb, Wm, nullptr, bm, eout);
}

// Round 20
// 340.693 us; speedup vs baseline: 1.0782x; 1.0782x over previous
//
#include <hip/hip_runtime.h>
#include <cstdint>
#include <cstddef>

#define NN 50000
#define EE 800000
#define NT 5   // 16-edge tiles per wave; 2500 blocks * 4 waves * NT * 16 == EE

typedef short bf16x8 __attribute__((ext_vector_type(8)));
typedef float f32x4 __attribute__((ext_vector_type(4)));
typedef float fx4 __attribute__((ext_vector_type(4)));

static __device__ __forceinline__ ushort f2b(float f) {
  uint u = __builtin_bit_cast(uint, f);
  u += 0x7FFFu + ((u >> 16) & 1u);
  return (ushort)(u >> 16);
}
static __device__ __forceinline__ float b2f(ushort h) {
  return __builtin_bit_cast(float, ((uint)h) << 16);
}
static __device__ __forceinline__ uint pk2(float a, float b) {
  return (uint)f2b(a) | (((uint)f2b(b)) << 16);
}
static __device__ __forceinline__ void up8(uint4 u, float* o) {
  o[0] = b2f((ushort)(u.x & 0xFFFF)); o[1] = b2f((ushort)(u.x >> 16));
  o[2] = b2f((ushort)(u.y & 0xFFFF)); o[3] = b2f((ushort)(u.y >> 16));
  o[4] = b2f((ushort)(u.z & 0xFFFF)); o[5] = b2f((ushort)(u.z >> 16));
  o[6] = b2f((ushort)(u.w & 0xFFFF)); o[7] = b2f((ushort)(u.w >> 16));
}
static __device__ __forceinline__ fx4 up4(uint2 u) {
  fx4 o;
  o[0] = b2f((ushort)(u.x & 0xFFFF)); o[1] = b2f((ushort)(u.x >> 16));
  o[2] = b2f((ushort)(u.y & 0xFFFF)); o[3] = b2f((ushort)(u.y >> 16));
  return o;
}
// build one MFMA frag word of a [K x 64] weight matrix (K=128 or K=64)
static __device__ __forceinline__ uint4 mk_frag(const float* W, int i) {
  int s2 = i >> 8, n = (i >> 6) & 3, lane = i & 63;
  int lo = lane & 15, hi = lane >> 4;
  ushort h[8];
#pragma unroll
  for (int j = 0; j < 8; j++) h[j] = f2b(W[(s2 * 32 + hi * 8 + j) * 64 + lo + 16 * n]);
  uint4 u;
  u.x = (uint)h[0] | ((uint)h[1] << 16); u.y = (uint)h[2] | ((uint)h[3] << 16);
  u.z = (uint)h[4] | ((uint)h[5] << 16); u.w = (uint)h[6] | ((uint)h[7] << 16);
  return u;
}

// ---------- K0: pack Wm/We/Wl/Wr into MFMA frag-ordered uint4 tables ----------
__global__ __launch_bounds__(256) void k_prep(const float* __restrict__ Wm,
                                              const float* __restrict__ We,
                                              const float* __restrict__ Wl,
                                              const float* __restrict__ Wr,
                                              uint4* __restrict__ wmP,
                                              uint4* __restrict__ weP,
                                              uint4* __restrict__ wlP,
                                              uint4* __restrict__ wrP) {
  int idx = blockIdx.x * 256 + threadIdx.x;  // 10 blocks * 256 = 2560
  if (idx < 1024) wmP[idx] = mk_frag(Wm, idx);
  else if (idx < 1536) weP[idx - 1024] = mk_frag(We, idx - 1024);
  else if (idx < 2048) wlP[idx - 1536] = mk_frag(Wl, idx - 1536);
  else if (idx < 2560) wrP[idx - 2048] = mk_frag(Wr, idx - 2048);
}

// ---------- K1 (ws path): xlb = bf16(x@Wl), xrb = bf16(x@Wr) via MFMA ----------
__global__ __launch_bounds__(256) void k_node_linear_mfma(
    const float* __restrict__ x, const uint4* __restrict__ wlP,
    const uint4* __restrict__ wrP, ushort* __restrict__ xlb,
    ushort* __restrict__ xrb, int n) {
  __shared__ float sT[4][2][16 * 68];
  int tid = threadIdx.x;
  int w = tid >> 6, l = tid & 63;
  int lo16 = l & 15, hi4 = l >> 4;
  bf16x8 awl[4][2], awr[4][2];
#pragma unroll
  for (int s = 0; s < 2; s++)
#pragma unroll
    for (int nn = 0; nn < 4; nn++) {
      awl[nn][s] = __builtin_bit_cast(bf16x8, wlP[(s * 4 + nn) * 64 + l]);
      awr[nn][s] = __builtin_bit_cast(bf16x8, wrP[(s * 4 + nn) * 64 + l]);
    }
  int ntile = (blockIdx.x * 4 + w) * 16;
  if (ntile >= n) return;
  int node = ntile + lo16;
  bf16x8 bfr[2];
#pragma unroll
  for (int s2 = 0; s2 < 2; s2++) {
    const fx4* p = (const fx4*)(x + (size_t)node * 64 + s2 * 32 + hi4 * 8);
    fx4 f0 = p[0];
    fx4 f1 = p[1];
    uint4 u;
    u.x = pk2(f0[0], f0[1]); u.y = pk2(f0[2], f0[3]);
    u.z = pk2(f1[0], f1[1]); u.w = pk2(f1[2], f1[3]);
    bfr[s2] = __builtin_bit_cast(bf16x8, u);
  }
  f32x4 z4 = {0.f, 0.f, 0.f, 0.f};
  f32x4 accl[4] = {z4, z4, z4, z4};
  f32x4 accr[4] = {z4, z4, z4, z4};
#pragma unroll
  for (int s2 = 0; s2 < 2; s2++)
#pragma unroll
    for (int nn = 0; nn < 4; nn++) {
      accl[nn] = __builtin_amdgcn_mfma_f32_16x16x32_bf16(awl[nn][s2], bfr[s2], accl[nn], 0, 0, 0);
      accr[nn] = __builtin_amdgcn_mfma_f32_16x16x32_bf16(awr[nn][s2], bfr[s2], accr[nn], 0, 0, 0);
    }
#pragma unroll
  for (int nn = 0; nn < 4; nn++)
#pragma unroll
    for (int r = 0; r < 4; r++) {
      sT[w][0][lo16 * 68 + hi4 * 4 + r + 16 * nn] = accl[nn][r];
      sT[w][1][lo16 * 68 + hi4 * 4 + r + 16 * nn] = accr[nn][r];
    }
  int m2 = l >> 2, q2 = l & 3;
#pragma unroll
  for (int b = 0; b < 2; b++) {
    float v[16];
#pragma unroll
    for (int c = 0; c < 16; c++) v[c] = sT[w][b][m2 * 68 + q2 * 16 + c];
    uint4 u0, u1;
    u0.x = pk2(v[0], v[1]);  u0.y = pk2(v[2], v[3]);
    u0.z = pk2(v[4], v[5]);  u0.w = pk2(v[6], v[7]);
    u1.x = pk2(v[8], v[9]);  u1.y = pk2(v[10], v[11]);
    u1.z = pk2(v[12], v[13]); u1.w = pk2(v[14], v[15]);
    ushort* dst = (b ? xrb : xlb) + (size_t)(ntile + m2) * 64 + q2 * 16;
    ((uint4*)dst)[0] = u0;
    ((uint4*)dst)[1] = u1;
  }
}

// ---------- K1 fallback: f32 xl/xr via VALU ----------
__global__ __launch_bounds__(256, 3) void k_node_linear(
    const float* __restrict__ x, const float* __restrict__ Wl,
    const float* __restrict__ Wr, float* __restrict__ xl,
    float* __restrict__ xr, int n) {
  int i = blockIdx.x * 256 + threadIdx.x;
  if (i >= n) return;
  const float4* px = (const float4*)(x + (size_t)i * 64);
  float accl[64], accr[64];
#pragma unroll
  for (int c = 0; c < 64; c++) { accl[c] = 0.f; accr[c] = 0.f; }
  for (int kq = 0; kq < 16; kq++) {
    float4 v = px[kq];
#pragma unroll
    for (int j = 0; j < 4; j++) {
      float xv = (j == 0) ? v.x : (j == 1) ? v.y : (j == 2) ? v.z : v.w;
      const float* wl = Wl + (kq * 4 + j) * 64;
      const float* wr = Wr + (kq * 4 + j) * 64;
#pragma unroll
      for (int c = 0; c < 64; c++) {
        accl[c] = fmaf(xv, wl[c], accl[c]);
        accr[c] = fmaf(xv, wr[c], accr[c]);
      }
    }
  }
  float4* pl = (float4*)(xl + (size_t)i * 64);
  float4* pr = (float4*)(xr + (size_t)i * 64);
#pragma unroll
  for (int q = 0; q < 16; q++) {
    float4 a, b;
    a.x = accl[4 * q]; a.y = accl[4 * q + 1]; a.z = accl[4 * q + 2]; a.w = accl[4 * q + 3];
    b.x = accr[4 * q]; b.y = accr[4 * q + 1]; b.z = accr[4 * q + 2]; b.w = accr[4 * q + 3];
    pl[q] = a; pr[q] = b;
  }
}

// ---------- K2: logits via MFMA -> exp; gather + ea both software-pipelined ----------
template <bool PACKED>
__global__ __launch_bounds__(256) void k_edge_logits(
    const float* __restrict__ ea, const int* __restrict__ ei,
    const float* __restrict__ We, const float* __restrict__ att,
    const float* __restrict__ xl, const float* __restrict__ xr,
    const ushort* __restrict__ xlb, const ushort* __restrict__ xrb,
    const uint4* __restrict__ weP, float* __restrict__ pexp,
    int* __restrict__ counts) {
  int tid = threadIdx.x;
  int w = tid >> 6, l = tid & 63;
  int lo16 = l & 15, hi4 = l >> 4;
  bf16x8 aw[4][2];
  if (PACKED) {
#pragma unroll
    for (int s = 0; s < 2; s++)
#pragma unroll
      for (int n = 0; n < 4; n++)
        aw[n][s] = __builtin_bit_cast(bf16x8, weP[(s * 4 + n) * 64 + l]);
  } else {
    for (int n = 0; n < 4; n++)
      for (int s = 0; s < 2; s++)
        aw[n][s] = __builtin_bit_cast(bf16x8, mk_frag(We, (s * 4 + n) * 64 + l));
  }
  float att4[4][4];
#pragma unroll
  for (int n = 0; n < 4; n++) {
    float4 a = *(const float4*)(att + 16 * n + hi4 * 4);
    att4[n][0] = a.x; att4[n][1] = a.y; att4[n][2] = a.z; att4[n][3] = a.w;
  }
  int wgid = blockIdx.x * 4 + w;
  int ebase = wgid * NT * 16;
  int sj = ei[ebase + lo16], dj = ei[EE + ebase + lo16];
  uint2 grl[4], grr[4];
  if (PACKED) {
#pragma unroll
    for (int n = 0; n < 4; n++) {
      grl[n] = *(const uint2*)(xlb + (size_t)sj * 64 + 16 * n + hi4 * 4);
      grr[n] = *(const uint2*)(xrb + (size_t)dj * 64 + 16 * n + hi4 * 4);
    }
  }
  fx4 ear[4];
#pragma unroll
  for (int s2 = 0; s2 < 2; s2++) {
    const fx4* p = (const fx4*)(ea + (size_t)(ebase + lo16) * 64 + s2 * 32 + hi4 * 8);
    ear[s2 * 2] = p[0];
    ear[s2 * 2 + 1] = p[1];
  }
  for (int it = 0; it < NT; it++) {
    int er = ebase + it * 16 + lo16;
    int djc = dj;
    fx4 gl[4], gr[4];
    if (!PACKED) {
#pragma unroll
      for (int n = 0; n < 4; n++) {
        gl[n] = *(const fx4*)(xl + (size_t)sj * 64 + 16 * n + hi4 * 4);
        gr[n] = *(const fx4*)(xr + (size_t)dj * 64 + 16 * n + hi4 * 4);
      }
    }
    int sjn = 0, djn = 0;
    if (it + 1 < NT) {
      sjn = ei[er + 16];
      djn = ei[EE + er + 16];
    }
    bf16x8 bfr[2];
#pragma unroll
    for (int s2 = 0; s2 < 2; s2++) {
      fx4 f0 = ear[s2 * 2], f1 = ear[s2 * 2 + 1];
      uint4 u;
      u.x = pk2(f0[0], f0[1]); u.y = pk2(f0[2], f0[3]);
      u.z = pk2(f1[0], f1[1]); u.w = pk2(f1[2], f1[3]);
      bfr[s2] = __builtin_bit_cast(bf16x8, u);
    }
    if (it + 1 < NT) {
#pragma unroll
      for (int s2 = 0; s2 < 2; s2++) {
        const fx4* p = (const fx4*)(ea + (size_t)(er + 16) * 64 + s2 * 32 + hi4 * 8);
        ear[s2 * 2] = p[0];
        ear[s2 * 2 + 1] = p[1];
      }
    }
    f32x4 z4 = {0.f, 0.f, 0.f, 0.f};
    f32x4 acc[4] = {z4, z4, z4, z4};
#pragma unroll
    for (int s2 = 0; s2 < 2; s2++)
#pragma unroll
      for (int n = 0; n < 4; n++)
        acc[n] = __builtin_amdgcn_mfma_f32_16x16x32_bf16(aw[n][s2], bfr[s2], acc[n], 0, 0, 0);
    if (PACKED) {
#pragma unroll
      for (int n = 0; n < 4; n++) { gl[n] = up4(grl[n]); gr[n] = up4(grr[n]); }
    }
    float lg[4];
#pragma unroll
    for (int n = 0; n < 4; n++) {
      float s = 0.f;
#pragma unroll
      for (int r = 0; r < 4; r++) {
        float z = acc[n][r] + gl[n][r] + gr[n][r];
        z = (z >= 0.f) ? z : 0.2f * z;
        s += z * att4[n][r];
      }
      s += __shfl_xor(s, 16, 64);
      s += __shfl_xor(s, 32, 64);
      lg[n] = s;
    }
    if (hi4 == 0) {
      // store exp(logit): max-subtraction unnecessary (|logit| ~ O(1)) and
      // softmax is shift-invariant.
      fx4 o = {__expf(lg[0]), __expf(lg[1]), __expf(lg[2]), __expf(lg[3])};
      ((fx4*)pexp)[er] = o;
      atomicAdd(&counts[djc], 1);
    }
    if (it + 1 < NT) {
      sj = sjn; dj = djn;
      if (PACKED) {
#pragma unroll
        for (int n = 0; n < 4; n++) {
          grl[n] = *(const uint2*)(xlb + (size_t)sj * 64 + 16 * n + hi4 * 4);
          grr[n] = *(const uint2*)(xrb + (size_t)dj * 64 + 16 * n + hi4 * 4);
        }
      }
    }
  }
}

// ---------- K3a/b/c: hierarchical exclusive scan of counts ----------
__global__ __launch_bounds__(256) void k_scan_sum(const int* __restrict__ counts,
                                                  int* __restrict__ bsum, int n) {
  __shared__ int red[256];
  int t = threadIdx.x;
  int idx = blockIdx.x * 256 + t;
  red[t] = (idx < n) ? counts[idx] : 0;
  __syncthreads();
  for (int off = 128; off > 0; off >>= 1) {
    if (t < off) red[t] += red[t + off];
    __syncthreads();
  }
  if (t == 0) bsum[blockIdx.x] = red[0];
}
__global__ __launch_bounds__(256) void k_scan_blk(const int* __restrict__ bsum,
                                                  int* __restrict__ boff,
                                                  int* __restrict__ offsets_end, int nb) {
  __shared__ int tmp[256];
  int t = threadIdx.x;
  int v = (t < nb) ? bsum[t] : 0;
  tmp[t] = v;
  __syncthreads();
  for (int off = 1; off < 256; off <<= 1) {
    int u = (t >= off) ? tmp[t - off] : 0;
    __syncthreads();
    tmp[t] += u;
    __syncthreads();
  }
  if (t < nb) boff[t] = tmp[t] - v;
  if (t == 255) offsets_end[0] = tmp[255];
}
__global__ __launch_bounds__(256) void k_scan_apply(const int* __restrict__ counts,
                                                    const int* __restrict__ boff,
                                                    int* __restrict__ offsets,
                                                    int* __restrict__ cursor, int n) {
  __shared__ int tmp[256];
  int t = threadIdx.x;
  int idx = blockIdx.x * 256 + t;
  int v = (idx < n) ? counts[idx] : 0;
  tmp[t] = v;
  __syncthreads();
  for (int off = 1; off < 256; off <<= 1) {
    int u = (t >= off) ? tmp[t - off] : 0;
    __syncthreads();
    tmp[t] += u;
    __syncthreads();
  }
  if (idx < n) {
    int ex = boff[blockIdx.x] + tmp[t] - v;
    offsets[idx] = ex;
    cursor[idx] = ex;
  }
}

// ---------- K4: scatter src + pexp payload into CSR order ----------
__global__ __launch_bounds__(256) void k_scatter(const int* __restrict__ ei,
                                                 const float* __restrict__ pexp,
                                                 int* __restrict__ cursor,
                                                 int* __restrict__ srcs,
                                                 float* __restrict__ pscr, int ne) {
  int e = blockIdx.x * blockDim.x + threadIdx.x;
  if (e < ne) {
    int d = ei[EE + e];
    int s = ei[e];
    fx4 p = ((const fx4*)pexp)[e];
    int pos = atomicAdd(&cursor[d], 1);
    srcs[pos] = s;
    ((fx4*)pscr)[pos] = p;
  }
}

// ---------- K5: segment aggregate over CSR-ordered payload ----------
template <bool BF>
__global__ __launch_bounds__(256) void k_node_agg(
    const int* __restrict__ offsets, const int* __restrict__ srcs,
    const float* __restrict__ pscr, const float* __restrict__ xl,
    const ushort* __restrict__ xlb, const float* __restrict__ bias,
    float* __restrict__ xout, ushort* __restrict__ xb, int n) {
  int tid = threadIdx.x;
  int y = tid >> 6, l = tid & 63;
  int h = l >> 4;
  float bv = bias[l];
  int i = blockIdx.x * 4 + y;
  if (i >= n) return;  // wave-uniform
  int beg = offsets[i], end = offsets[i + 1];
  float den = 0.f, acc = 0.f;
  for (int c0 = beg; c0 < end; c0 += 64) {
    int cnt = min(64, end - c0);
    int s_l = (l < cnt) ? srcs[c0 + l] : 0;   // coalesced
    for (int j = 0; j < cnt; j += 8) {
      int nb8 = min(8, cnt - j);
      float pv[8], xvf[8];
      ushort xvb[8];
#pragma unroll
      for (int u = 0; u < 8; u++) {
        if (u < nb8) {
          int su = __shfl(s_l, j + u, 64);
          pv[u] = pscr[(size_t)(c0 + j + u) * 4 + h];   // sequential in node range
          if (BF) xvb[u] = xlb[(size_t)su * 64 + l];
          else xvf[u] = xl[(size_t)su * 64 + l];
        }
      }
#pragma unroll
      for (int u = 0; u < 8; u++) {
        if (u < nb8) {
          den += pv[u];
          acc = fmaf(pv[u], BF ? b2f(xvb[u]) : xvf[u], acc);
        }
      }
    }
  }
  float o = acc / (den + 1e-16f) + bv;
  xout[(size_t)i * 64 + l] = o;
  if (BF) xb[(size_t)i * 64 + l] = f2b(o);
}

// ---------- K6: edge MLP via MFMA, software-pipelined, weights in registers (R18 exact) ----------
template <bool PACKED>
__global__ __launch_bounds__(256) void k_edge_mlp(
    const float* __restrict__ ea, const int* __restrict__ ei,
    const float* __restrict__ xoutf, const ushort* __restrict__ xb,
    const float* __restrict__ lng, const float* __restrict__ lnb,
    const float* __restrict__ Wm, const uint4* __restrict__ wmP,
    const float* __restrict__ bm, float* __restrict__ eout) {
  __shared__ float sT[4][16 * 68];
  int tid = threadIdx.x;
  int w = tid >> 6, l = tid & 63;
  int lo16 = l & 15, hi4 = l >> 4;
  bf16x8 bwm[4][4];
  if (PACKED) {
#pragma unroll
    for (int s2 = 0; s2 < 4; s2++)
#pragma unroll
      for (int n = 0; n < 4; n++)
        bwm[n][s2] = __builtin_bit_cast(bf16x8, wmP[(s2 * 4 + n) * 64 + l]);
  } else {
    for (int n = 0; n < 4; n++)
      for (int s2 = 0; s2 < 4; s2++)
        bwm[n][s2] = __builtin_bit_cast(bf16x8, mk_frag(Wm, (s2 * 4 + n) * 64 + l));
  }
  float bmv[4];
#pragma unroll
  for (int n = 0; n < 4; n++) bmv[n] = bm[lo16 + 16 * n];

  int wgid = blockIdx.x * 4 + w;
  int ebase = wgid * NT * 16;
  int m2 = l >> 2, q2 = l & 3;

  int sj = ei[ebase + lo16], dj = ei[EE + ebase + lo16];
  uint4 pf0, pf1, pf2, pf3;
  if (PACKED) {
    pf0 = *(const uint4*)(xb + (size_t)sj * 64 + hi4 * 8);
    pf1 = *(const uint4*)(xb + (size_t)sj * 64 + 32 + hi4 * 8);
    pf2 = *(const uint4*)(xb + (size_t)dj * 64 + hi4 * 8);
    pf3 = *(const uint4*)(xb + (size_t)dj * 64 + 32 + hi4 * 8);
  }
  for (int it = 0; it < NT; it++) {
    int e0 = ebase + it * 16;
    float vv[4][8];
    if (PACKED) {
      up8(pf0, vv[0]); up8(pf1, vv[1]); up8(pf2, vv[2]); up8(pf3, vv[3]);
    } else {
#pragma unroll
      for (int s2 = 0; s2 < 4; s2++) {
        const float* src = (s2 < 2) ? (xoutf + (size_t)sj * 64 + (s2 & 1) * 32 + hi4 * 8)
                                    : (xoutf + (size_t)dj * 64 + (s2 & 1) * 32 + hi4 * 8);
        float4 a = *(const float4*)src;
        float4 b = *(const float4*)(src + 4);
        vv[s2][0] = a.x; vv[s2][1] = a.y; vv[s2][2] = a.z; vv[s2][3] = a.w;
        vv[s2][4] = b.x; vv[s2][5] = b.y; vv[s2][6] = b.z; vv[s2][7] = b.w;
      }
    }
    int sjn = 0, djn = 0;
    if (it + 1 < NT) {
      sjn = ei[e0 + 16 + lo16];
      djn = ei[EE + e0 + 16 + lo16];
    }
    float sm = 0.f, sq = 0.f;
#pragma unroll
    for (int s2 = 0; s2 < 4; s2++)
#pragma unroll
      for (int j = 0; j < 8; j++) { sm += vv[s2][j]; sq += vv[s2][j] * vv[s2][j]; }
    sm += __shfl_xor(sm, 16, 64); sm += __shfl_xor(sm, 32, 64);
    sq += __shfl_xor(sq, 16, 64); sq += __shfl_xor(sq, 32, 64);
    float mean = sm * (1.f / 128.f);
    float var = sq * (1.f / 128.f) - mean * mean;
    float rs = rsqrtf(var + 1e-5f);
    f32x4 acc[4];
#pragma unroll
    for (int n = 0; n < 4; n++) {
      f32x4 c = {bmv[n], bmv[n], bmv[n], bmv[n]};
      acc[n] = c;
    }
#pragma unroll
    for (int s2 = 0; s2 < 4; s2++) {
      float4 ga = *(const float4*)(lng + s2 * 32 + hi4 * 8);
      float4 gb = *(const float4*)(lng + s2 * 32 + hi4 * 8 + 4);
      float4 ba = *(const float4*)(lnb + s2 * 32 + hi4 * 8);
      float4 bb = *(const float4*)(lnb + s2 * 32 + hi4 * 8 + 4);
      float g8[8] = {ga.x, ga.y, ga.z, ga.w, gb.x, gb.y, gb.z, gb.w};
      float b8[8] = {ba.x, ba.y, ba.z, ba.w, bb.x, bb.y, bb.z, bb.w};
      float h8[8];
#pragma unroll
      for (int j = 0; j < 8; j++)
        h8[j] = fmaxf(fmaf((vv[s2][j] - mean) * rs, g8[j], b8[j]), 0.f);
      uint4 u;
      u.x = pk2(h8[0], h8[1]); u.y = pk2(h8[2], h8[3]);
      u.z = pk2(h8[4], h8[5]); u.w = pk2(h8[6], h8[7]);
      bf16x8 afr = __builtin_bit_cast(bf16x8, u);
#pragma unroll
      for (int n = 0; n < 4; n++)
        acc[n] = __builtin_amdgcn_mfma_f32_16x16x32_bf16(afr, bwm[n][s2], acc[n], 0, 0, 0);
    }
    if (it + 1 < NT) {
      if (PACKED) {
        pf0 = *(const uint4*)(xb + (size_t)sjn * 64 + hi4 * 8);
        pf1 = *(const uint4*)(xb + (size_t)sjn * 64 + 32 + hi4 * 8);
        pf2 = *(const uint4*)(xb + (size_t)djn * 64 + hi4 * 8);
        pf3 = *(const uint4*)(xb + (size_t)djn * 64 + 32 + hi4 * 8);
      }
      sj = sjn; dj = djn;
    }
#pragma unroll
    for (int n = 0; n < 4; n++)
#pragma unroll
      for (int r = 0; r < 4; r++)
        sT[w][(hi4 * 4 + r) * 68 + lo16 + 16 * n] = acc[n][r];
#pragma unroll
    for (int c = 0; c < 4; c++) {
      fx4 t4 = *(const fx4*)&sT[w][m2 * 68 + q2 * 16 + 4 * c];
      size_t off = (size_t)(e0 + m2) * 64 + q2 * 16 + 4 * c;
      fx4 r4 = *(const fx4*)(ea + off);
      fx4 o = r4 + t4;
      *(fx4*)(eout + off) = o;
    }
  }
}

extern "C" void kernel_launch(void* const* d_in, const int* in_sizes, int n_in,
                              void* d_out, int out_size, void* d_ws, size_t ws_size,
                              hipStream_t stream) {
  const float* x   = (const float*)d_in[0];
  const int*   ei  = (const int*)d_in[1];
  const float* ea  = (const float*)d_in[2];
  const float* Wl  = (const float*)d_in[3];
  const float* Wr  = (const float*)d_in[4];
  const float* We  = (const float*)d_in[5];
  const float* att = (const float*)d_in[6];
  const float* cb  = (const float*)d_in[7];
  const float* lng = (const float*)d_in[8];
  const float* lnb = (const float*)d_in[9];
  const float* Wm  = (const float*)d_in[10];
  const float* bm  = (const float*)d_in[11];

  float* out  = (float*)d_out;
  float* xout = out;                       // [N,64]
  float* eout = out + (size_t)NN * 64;     // [E,64]

  const int nb = (NN + 255) / 256;         // 196 scan blocks
  const int egrid = EE / (4 * NT * 16);    // 2500 blocks for edge kernels

  size_t packBytes = (size_t)(1024 + 512 + 512 + 512) * 16;        // wmP+weP+wlP+wrP
  size_t fWords    = (size_t)NN * 64 * 2 + (size_t)EE * 4 * 2;     // xl, xr, pexp, pscr
  size_t xbWords   = (size_t)NN * 64 / 2;                          // bf16 x_out
  size_t xlbWords  = (size_t)NN * 64 / 2;                          // bf16 xl
  size_t xrbWords  = (size_t)NN * 64 / 2;                          // bf16 xr
  size_t intWords  = (size_t)NN * 3 + 1 + (size_t)EE + 512;        // counts/off/cur/srcs/bsum/boff
  size_t needBytes = packBytes + (fWords + xbWords + xlbWords + xrbWords + intWords) * 4;
  bool useWs = (ws_size >= needBytes);

  uint4*  wmP = useWs ? (uint4*)d_ws : nullptr;
  uint4*  weP = useWs ? wmP + 1024 : nullptr;
  uint4*  wlP = useWs ? weP + 512 : nullptr;
  uint4*  wrP = useWs ? wlP + 512 : nullptr;
  float*  fbase = useWs ? (float*)((char*)d_ws + packBytes) : eout;

  float*  xl      = fbase;
  float*  xr      = xl + (size_t)NN * 64;
  float*  pexp    = xr + (size_t)NN * 64;
  float*  pscr    = pexp + (size_t)EE * 4;
  ushort* xb      = useWs ? (ushort*)(pscr + (size_t)EE * 4) : nullptr;
  ushort* xlb     = useWs ? xb + (size_t)NN * 64 : nullptr;
  ushort* xrb     = useWs ? xlb + (size_t)NN * 64 : nullptr;
  int*    counts  = useWs ? (int*)(xrb + (size_t)NN * 64)
                          : (int*)(pscr + (size_t)EE * 4);
  int*    offsets = counts + NN;
  int*    cursor  = offsets + NN + 1;
  int*    srcs    = cursor + NN;
  int*    bsum    = srcs + EE;
  int*    boff    = bsum + 256;

  hipMemsetAsync(counts, 0, NN * sizeof(int), stream);
  if (useWs) {
    k_prep<<<10, 256, 0, stream>>>(Wm, We, Wl, Wr, wmP, weP, wlP, wrP);
    k_node_linear_mfma<<<(NN / 16 + 3) / 4, 256, 0, stream>>>(x, wlP, wrP, xlb, xrb, NN);
    k_edge_logits<true><<<egrid, 256, 0, stream>>>(ea, ei, We, att, xl, xr, xlb, xrb, weP, pexp, counts);
  } else {
    k_node_linear<<<(NN + 255) / 256, 256, 0, stream>>>(x, Wl, Wr, xl, xr, NN);
    k_edge_logits<false><<<egrid, 256, 0, stream>>>(ea, ei, We, att, xl, xr, nullptr, nullptr, nullptr, pexp, counts);
  }
  k_scan_sum<<<nb, 256, 0, stream>>>(counts, bsum, NN);
  k_scan_blk<<<1, 256, 0, stream>>>(bsum, boff, offsets + NN, nb);
  k_scan_apply<<<nb, 256, 0, stream>>>(counts, boff, offsets, cursor, NN);
  k_scatter<<<(EE + 255) / 256, 256, 0, stream>>>(ei, pexp, cursor, srcs, pscr, EE);
  if (useWs)
    k_node_agg<true><<<(NN + 3) / 4, 256, 0, stream>>>(offsets, srcs, pscr, xl, xlb, cb, xout, xb, NN);
  else
    k_node_agg<false><<<(NN + 3) / 4, 256, 0, stream>>>(offsets, srcs, pscr, xl, nullptr, cb, xout, nullptr, NN);
  if (useWs)
    k_edge_mlp<true><<<egrid, 256, 0, stream>>>(ea, ei, xout, xb, lng, lnb, Wm, wmP, bm, eout);
  else
    k_edge_mlp<false><<<egrid, 256, 0, stream>>>(ea, ei, xout, nullptr, lng, lnb, Wm, nullptr, bm, eout);
}